// Round 6
// baseline (371.681 us; speedup 1.0000x reference)
//
#include <hip/hip_runtime.h>
#include <hip/hip_bf16.h>

#define NN 50000
#define EE 600000
#define HH 128
#define CC 40
#define NEG 0.1f
#define CAP 40      // padded-CSR capacity; P(deg>40) ~ 1e-10 for Binom(600k, 1/50k)
#define NSLOT 50176 // 16-padded class-sorted slots
#define NBLK (NSLOT / 16)   // 3136

typedef __attribute__((ext_vector_type(8))) short bf16x8;
typedef __attribute__((ext_vector_type(4))) float f32x4;
typedef __attribute__((ext_vector_type(4))) unsigned uint4v;   // clang vector: ok for nontemporal builtins

__device__ __forceinline__ unsigned short f2bf(float f) {
    unsigned u = __float_as_uint(f);
    unsigned r = u + 0x7fffu + ((u >> 16) & 1u);
    return (unsigned short)(r >> 16);
}
__device__ __forceinline__ float bfhi(unsigned v) { return __uint_as_float(v & 0xFFFF0000u); }
__device__ __forceinline__ float bflo(unsigned v) { return __uint_as_float(v << 16); }

// ---------------- padded-CSR build: one edge per thread; ushort entries ----------------
__global__ void k_build(const int* __restrict__ src, const int* __restrict__ dst,
                        int* __restrict__ counts, unsigned short* __restrict__ csr) {
    int e = blockIdx.x * blockDim.x + threadIdx.x;
    if (e < EE) {
        int d = dst[e];
        if ((unsigned)d < (unsigned)NN) {
            int sl = atomicAdd(&counts[d], 1);
            if (sl < CAP) csr[d * CAP + sl] = (unsigned short)src[e];
        }
    }
}

// ---------------- degree-class sort: hist -> prefix -> place ----------------
__global__ void k_hist(const int* __restrict__ counts, int* __restrict__ hist) {
    __shared__ int lh[16];
    if (threadIdx.x < 16) lh[threadIdx.x] = 0;
    __syncthreads();
    int n = blockIdx.x * 256 + threadIdx.x;
    if (n < NN) {
        int c = counts[n]; c = c < CAP ? c : CAP;
        atomicAdd(&lh[(c + 3) >> 2], 1);
    }
    __syncthreads();
    if (threadIdx.x < 11) atomicAdd(&hist[threadIdx.x], lh[threadIdx.x]);
}

__global__ void k_prefix(const int* __restrict__ hist, int* __restrict__ base) {
    if (threadIdx.x == 0) {
        int acc = 0;
        for (int r = 10; r >= 0; --r) {   // descending: long blocks first
            base[r] = acc;
            acc += (hist[r] + 15) & ~15;
        }
    }
}

// hierarchical-atomic place: LDS class counts -> 1 global atomic per class per block
__global__ void k_place(const int* __restrict__ counts, const int* __restrict__ base,
                        int* __restrict__ fill, unsigned* __restrict__ perm) {
    __shared__ int lcnt[16];
    __shared__ int lbase[16];
    int t = threadIdx.x;
    if (t < 16) lcnt[t] = 0;
    __syncthreads();
    int n = blockIdx.x * 256 + t;
    int r = 0, lslot = 0, c = 0;
    if (n < NN) {
        c = counts[n]; c = c < CAP ? c : CAP;
        r = (c + 3) >> 2;
        lslot = atomicAdd(&lcnt[r], 1);
    }
    __syncthreads();
    if (t < 11 && lcnt[t] > 0) lbase[t] = atomicAdd(&fill[t], lcnt[t]);
    __syncthreads();
    if (n < NN) {
        int slot = base[r] + lbase[r] + lslot;
        if (slot >= 0 && slot < NSLOT) perm[slot] = (unsigned)n | ((unsigned)c << 16);
    }
}

// ---------------- k_prep: weight swizzle + counts zero + x->bf16 + perm/aux init ----------------
struct PrepArgs {
    const float* wsrc[8];
    unsigned short* wdst[8];
    int* counts;
    const float* x;
    unsigned* xb;
    unsigned* perm;
    int* aux;
};

template <int DOUT, int DOUTP>
__device__ __forceinline__ void swz_one(const float* __restrict__ W,
                                        unsigned short* __restrict__ dstf, int idx) {
    int k = idx / DOUTP, n = idx % DOUTP;
    unsigned short val = (n < DOUT) ? f2bf(W[k * DOUT + n]) : (unsigned short)0;
    int kt = k >> 5, kin = k & 31, nt = n >> 4, nin = n & 15;
    int lane = ((kin >> 3) << 4) | nin;
    int j = kin & 7;
    int NT = DOUTP >> 4;
    dstf[(((kt * NT + nt) * 64) + lane) * 8 + j] = val;
}

#define XCB ((NN * HH / 4 + 255) / 256)   // 6250 xcast blocks
#define PFB ((NSLOT + 255) / 256)         // 196 perm-fill blocks

__global__ void k_prep(PrepArgs a) {
    int b = blockIdx.x;
    if (b < 384) {
        int tid = b * 256 + threadIdx.x;
        if (tid < NN) a.counts[tid] = 0;
        int which = b >> 6;
        int idx = (b & 63) * 256 + threadIdx.x;
        swz_one<HH, HH>(a.wsrc[which], a.wdst[which], idx);
    } else if (b < 432) {
        int bb = b - 384;
        int which = 6 + bb / 24;
        int idx = (bb % 24) * 256 + threadIdx.x;
        swz_one<CC, 48>(a.wsrc[which], a.wdst[which], idx);
    } else if (b < 432 + XCB) {
        int t = (b - 432) * 256 + threadIdx.x;
        if (t < NN * HH / 4) {
            float4 v = ((const float4*)a.x)[t];
            uint2 o;
            o.x = ((unsigned)f2bf(v.y) << 16) | f2bf(v.x);
            o.y = ((unsigned)f2bf(v.w) << 16) | f2bf(v.z);
            ((uint2*)a.xb)[t] = o;
        }
    } else {
        int i = (b - (432 + XCB)) * 256 + threadIdx.x;
        if (i < NSLOT) a.perm[i] = 0xFFFFFFFFu;   // sentinel
        if (i < 64) a.aux[i] = 0;                  // hist + fill
    }
}

// ---------------- gather batch: indices from SGPR-resident csr words, nt row loads ----------------
// cw[] holds the wave's whole csr list (ushort x4 per ull), loaded via the SCALAR path.
// Per round r (literal): lane extracts its slot's index from SGPRs (2-3 VALU), clamps,
// issues one nt dwordx4 gather. No vector csr loads at all.
template <int R>
__device__ __forceinline__ void gather_batch(const unsigned long long* cw,
                                             const uint4v* __restrict__ hw4,
                                             int s, int sh16, int gg, int cnt, int base_r,
                                             float (&acc)[8]) {
    uint4v vb[R];
#pragma unroll
    for (int r = 0; r < R; ++r) {
        unsigned long long w = cw[base_r + r];
        unsigned half = (s & 2) ? (unsigned)(w >> 32) : (unsigned)w;
        unsigned idx = (half >> sh16) & 0xffffu;
        idx = idx < (unsigned)NN ? idx : 0u;
        vb[r] = __builtin_nontemporal_load(hw4 + (size_t)idx * 16 + gg);
    }
#pragma unroll
    for (int r = 0; r < R; ++r) {
        if ((base_r + r) * 4 + s < cnt) {
            acc[0] += bflo(vb[r].x); acc[1] += bfhi(vb[r].x);
            acc[2] += bflo(vb[r].y); acc[3] += bfhi(vb[r].y);
            acc[4] += bflo(vb[r].z); acc[5] += bfhi(vb[r].z);
            acc[6] += bflo(vb[r].w); acc[7] += bfhi(vb[r].w);
        }
    }
}

// ---------------- layer kernel: scalar-path csr, nt gathers, double GEMM + lrelu ----------------
// Block = 1024 thr = 16 waves = 16 slots (1 node/wave). lane = s*16+gg: s = edge slot 0..3,
// gg = uint4 dim-group (full 256B row per round). Wave-uniform scalar switch on rounds.
template <int MODE>
__global__ __launch_bounds__(1024, 8) void k_layer(
    const unsigned short* __restrict__ hin,    // [N][128] bf16 (node space)
    const unsigned* __restrict__ perm,         // [NSLOT] node|cnt<<16
    const unsigned short* __restrict__ csr,    // [N][CAP] ushort src ids
    const unsigned short* __restrict__ B1f, const unsigned short* __restrict__ B2f,
    const float* __restrict__ bias, unsigned short* __restrict__ out,
    const unsigned short* __restrict__ Tf, unsigned short* __restrict__ tOut) {
    __shared__ unsigned lds[16][72];
    __shared__ int nodeTab[16];
    int wid = threadIdx.x >> 6;
    int lane = threadIdx.x & 63;
    int m0 = blockIdx.x * 16;
    int gg = lane & 15;
    int s = lane >> 4;
    int sh16 = (s & 1) * 16;
    const uint4v* hw4 = (const uint4v*)hin;

    // wave-uniform perm entry via scalar path
    int slot = __builtin_amdgcn_readfirstlane(m0 + wid);
    unsigned pe = perm[slot];
    int node = (int)(pe & 0xffffu);
    int cnt = (int)((pe >> 16) & 0xffffu);
    int valid = node < NN;
    if (lane == 0) nodeTab[wid] = valid ? node : (1 << 30);
    int rounds = valid ? (cnt + 3) >> 2 : 0;
    rounds = rounds < 10 ? rounds : 10;
    float sc = 1.0f / (float)((valid && cnt > 0) ? cnt : 1);

    // whole csr list (80B) via scalar loads, uniform base
    const unsigned long long* cr8 =
        (const unsigned long long*)(csr + (size_t)(valid ? node : 0) * CAP);
    unsigned long long cw[10];
#pragma unroll
    for (int r = 0; r < 10; ++r) cw[r] = cr8[r];

    float acc[8];
#pragma unroll
    for (int d = 0; d < 8; ++d) acc[d] = 0.f;

    switch (rounds) {   // scalar switch (class-sorted -> block-uniform)
        case 0: break;
        case 1: gather_batch<1>(cw, hw4, s, sh16, gg, cnt, 0, acc); break;
        case 2: gather_batch<2>(cw, hw4, s, sh16, gg, cnt, 0, acc); break;
        case 3: gather_batch<3>(cw, hw4, s, sh16, gg, cnt, 0, acc); break;
        case 4: gather_batch<4>(cw, hw4, s, sh16, gg, cnt, 0, acc); break;
        case 5: gather_batch<5>(cw, hw4, s, sh16, gg, cnt, 0, acc); break;
        case 6: gather_batch<3>(cw, hw4, s, sh16, gg, cnt, 0, acc);
                gather_batch<3>(cw, hw4, s, sh16, gg, cnt, 3, acc); break;
        case 7: gather_batch<4>(cw, hw4, s, sh16, gg, cnt, 0, acc);
                gather_batch<3>(cw, hw4, s, sh16, gg, cnt, 4, acc); break;
        case 8: gather_batch<4>(cw, hw4, s, sh16, gg, cnt, 0, acc);
                gather_batch<4>(cw, hw4, s, sh16, gg, cnt, 4, acc); break;
        case 9: gather_batch<5>(cw, hw4, s, sh16, gg, cnt, 0, acc);
                gather_batch<4>(cw, hw4, s, sh16, gg, cnt, 5, acc); break;
        default: gather_batch<5>(cw, hw4, s, sh16, gg, cnt, 0, acc);
                 gather_batch<5>(cw, hw4, s, sh16, gg, cnt, 5, acc); break;
    }

    // reduce over slot bits (lane bits 4,5)
#pragma unroll
    for (int d = 0; d < 8; ++d) {
        float t = acc[d];
        t += __shfl_xor(t, 16, 64);
        t += __shfl_xor(t, 32, 64);
        acc[d] = t * sc;
    }
    if (lane < 16) {   // s == 0, gg == lane
        unsigned w4[4];
        w4[0] = ((unsigned)f2bf(acc[1]) << 16) | f2bf(acc[0]);
        w4[1] = ((unsigned)f2bf(acc[3]) << 16) | f2bf(acc[2]);
        w4[2] = ((unsigned)f2bf(acc[5]) << 16) | f2bf(acc[4]);
        w4[3] = ((unsigned)f2bf(acc[7]) << 16) | f2bf(acc[6]);
        *(uint4v*)&lds[wid][gg * 4] = *(uint4v*)w4;
    }
    __syncthreads();

    // ---- MFMA: A1 from LDS, A2 = self row (via nodeTab); waves 0..7, 1 col-tile per wave ----
    int nin = lane & 15;
    int kq = lane >> 4;
    unsigned short hv[4];

    if (wid < 8) {
        const unsigned* arow = &lds[nin][0];
        int node2 = nodeTab[nin];
        int na = node2 < NN ? node2 : 0;
        f32x4 acc1 = (f32x4){0.f, 0.f, 0.f, 0.f};

#pragma unroll
        for (int kt = 0; kt < 4; ++kt) {
            bf16x8 a1 = *(const bf16x8*)(arow + kt * 16 + kq * 4);
            bf16x8 a2 = *(const bf16x8*)(hin + (size_t)na * HH + kt * 32 + kq * 8);
            bf16x8 b1 = *(const bf16x8*)(B1f + (((kt * 8 + wid) * 64) + lane) * 8);
            acc1 = __builtin_amdgcn_mfma_f32_16x16x32_bf16(a1, b1, acc1, 0, 0, 0);
            bf16x8 b2 = *(const bf16x8*)(B2f + (((kt * 8 + wid) * 64) + lane) * 8);
            acc1 = __builtin_amdgcn_mfma_f32_16x16x32_bf16(a2, b2, acc1, 0, 0, 0);
        }

        // C/D: col = lane&15, row = (lane>>4)*4 + reg; scatter rows by nodeTab
        int col = wid * 16 + nin;
        float bv = bias[col];
#pragma unroll
        for (int r = 0; r < 4; ++r) {
            float v = acc1[r] + bv;
            v = fmaxf(v, NEG * v);
            hv[r] = f2bf(v);
            int nm = nodeTab[kq * 4 + r];
            if (nm < NN) out[(size_t)nm * HH + col] = hv[r];
        }
    }

    if (MODE == 1) {
        // stage lrelu'd tile to LDS, then waves 0..2 compute t = tile @ dec_Wl (16x48)
        __syncthreads();
        unsigned short* lsh = (unsigned short*)&lds[0][0];   // [16][144] shorts
        if (wid < 8) {
            int col = wid * 16 + nin;
#pragma unroll
            for (int r = 0; r < 4; ++r) lsh[(kq * 4 + r) * 144 + col] = hv[r];
        }
        __syncthreads();
        if (wid < 3) {
            f32x4 at = (f32x4){0.f, 0.f, 0.f, 0.f};
#pragma unroll
            for (int kt = 0; kt < 4; ++kt) {
                bf16x8 a = *(const bf16x8*)&lsh[nin * 144 + kt * 32 + kq * 8];
                bf16x8 b = *(const bf16x8*)(Tf + (((kt * 3 + wid) * 64) + lane) * 8);
                at = __builtin_amdgcn_mfma_f32_16x16x32_bf16(a, b, at, 0, 0, 0);
            }
#pragma unroll
            for (int r = 0; r < 4; ++r) {
                int nm = nodeTab[kq * 4 + r];
                if (nm < NN) tOut[(size_t)nm * 48 + wid * 16 + nin] = f2bf(at[r]);
            }
        }
    }
}

// ---------------- k_dec gather batch: 8 slots x 6(+2 dup) uint4 groups, 96B rows ----------------
// entry index e = r*8+s -> ull word 2r+(s>>2), 32b half (s>>1)&1, 16b pos s&1.
template <int R>
__device__ __forceinline__ void gatherd_batch(const unsigned long long* cw,
                                              const uint4v* __restrict__ t4,
                                              int s, int sh16, int g6, int cnt,
                                              float (&acc)[8]) {
    uint4v vb[R];
#pragma unroll
    for (int r = 0; r < R; ++r) {
        unsigned long long w = (s & 4) ? cw[2 * r + 1] : cw[2 * r];
        unsigned half = (s & 2) ? (unsigned)(w >> 32) : (unsigned)w;
        unsigned idx = (half >> sh16) & 0xffffu;
        idx = idx < (unsigned)NN ? idx : 0u;
        vb[r] = __builtin_nontemporal_load(t4 + (size_t)idx * 6 + g6);
    }
#pragma unroll
    for (int r = 0; r < R; ++r) {
        if (r * 8 + s < cnt) {
            acc[0] += bflo(vb[r].x); acc[1] += bfhi(vb[r].x);
            acc[2] += bflo(vb[r].y); acc[3] += bfhi(vb[r].y);
            acc[4] += bflo(vb[r].z); acc[5] += bfhi(vb[r].z);
            acc[6] += bflo(vb[r].w); acc[7] += bfhi(vb[r].w);
        }
    }
}

// ---------------- k_dec: gather t + h1@Wr + bias + log_softmax ----------------
__global__ __launch_bounds__(1024, 8) void k_dec(
    const unsigned short* __restrict__ tbuf,   // [N][48] bf16, 96B rows
    const unsigned short* __restrict__ h1,
    const unsigned* __restrict__ perm,
    const unsigned short* __restrict__ csr,
    const unsigned short* __restrict__ B2f, const float* __restrict__ bias,
    float* __restrict__ out) {
    __shared__ float aggT[16][52];
    __shared__ int nodeTab[16];
    int wid = threadIdx.x >> 6;
    int lane = threadIdx.x & 63;
    int m0 = blockIdx.x * 16;
    int g = lane & 7;
    int g6 = g < 6 ? g : g - 6;        // lanes 6,7 duplicate slices 0,1 (same cache lines)
    int s = lane >> 3;                 // 8 edge-slots
    int sh16 = (s & 1) * 16;
    const uint4v* t4 = (const uint4v*)tbuf;

    int slot = __builtin_amdgcn_readfirstlane(m0 + wid);
    unsigned pe = perm[slot];
    int node = (int)(pe & 0xffffu);
    int cnt = (int)((pe >> 16) & 0xffffu);
    int valid = node < NN;
    if (lane == 0) nodeTab[wid] = valid ? node : (1 << 30);
    int rounds = valid ? (cnt + 7) >> 3 : 0;   // <= 5
    rounds = rounds < 5 ? rounds : 5;
    float sc = 1.0f / (float)((valid && cnt > 0) ? cnt : 1);

    const unsigned long long* cr8 =
        (const unsigned long long*)(csr + (size_t)(valid ? node : 0) * CAP);
    unsigned long long cw[10];
#pragma unroll
    for (int r = 0; r < 10; ++r) cw[r] = cr8[r];

    float acc[8];
#pragma unroll
    for (int d = 0; d < 8; ++d) acc[d] = 0.f;

    switch (rounds) {
        case 0: break;
        case 1: gatherd_batch<1>(cw, t4, s, sh16, g6, cnt, acc); break;
        case 2: gatherd_batch<2>(cw, t4, s, sh16, g6, cnt, acc); break;
        case 3: gatherd_batch<3>(cw, t4, s, sh16, g6, cnt, acc); break;
        case 4: gatherd_batch<4>(cw, t4, s, sh16, g6, cnt, acc); break;
        default: gatherd_batch<5>(cw, t4, s, sh16, g6, cnt, acc); break;
    }

    // reduce over slot bits (lane bits 3..5)
#pragma unroll
    for (int d = 0; d < 8; ++d) {
        float t = acc[d];
        t += __shfl_xor(t, 8, 64);
        t += __shfl_xor(t, 16, 64);
        t += __shfl_xor(t, 32, 64);
        acc[d] = t * sc;
    }
    if (s == 0 && g < 6) {
        float4 p0, p1;
        p0.x = acc[0]; p0.y = acc[1]; p0.z = acc[2]; p0.w = acc[3];
        p1.x = acc[4]; p1.y = acc[5]; p1.z = acc[6]; p1.w = acc[7];
        *(float4*)&aggT[wid][8 * g] = p0;
        *(float4*)&aggT[wid][8 * g + 4] = p1;
    }
    __syncthreads();
    if (wid != 0) return;

    int nin = lane & 15, kq = lane >> 4;
    int node2 = nodeTab[nin];
    int na = node2 < NN ? node2 : 0;
    f32x4 acc2[3];
#pragma unroll
    for (int j = 0; j < 3; ++j) acc2[j] = (f32x4){0.f, 0.f, 0.f, 0.f};
#pragma unroll
    for (int kt = 0; kt < 4; ++kt) {
        bf16x8 a2 = *(const bf16x8*)(h1 + (size_t)na * HH + kt * 32 + kq * 8);
#pragma unroll
        for (int j = 0; j < 3; ++j) {
            bf16x8 b2 = *(const bf16x8*)(B2f + (((kt * 3 + j) * 64) + lane) * 8);
            acc2[j] = __builtin_amdgcn_mfma_f32_16x16x32_bf16(a2, b2, acc2[j], 0, 0, 0);
        }
    }
    float bv[3];
#pragma unroll
    for (int t = 0; t < 3; ++t) {
        int col = t * 16 + nin;
        bv[t] = (col < CC) ? bias[col] : 0.f;
    }
#pragma unroll
    for (int r = 0; r < 4; ++r) {
        int ml = kq * 4 + r;
        int nm = nodeTab[ml];
        float v[3];
        float mx = -1e30f;
#pragma unroll
        for (int t = 0; t < 3; ++t) {
            int col = t * 16 + nin;
            v[t] = acc2[t][r] + aggT[ml][col] + bv[t];
            if (col < CC) mx = fmaxf(mx, v[t]);
        }
        for (int off = 1; off < 16; off <<= 1) mx = fmaxf(mx, __shfl_xor(mx, off, 64));
        float sm = 0.f;
#pragma unroll
        for (int t = 0; t < 3; ++t) {
            int col = t * 16 + nin;
            if (col < CC) sm += expf(v[t] - mx);
        }
        for (int off = 1; off < 16; off <<= 1) sm += __shfl_xor(sm, off, 64);
        float lse = mx + logf(sm);
#pragma unroll
        for (int t = 0; t < 3; ++t) {
            int col = t * 16 + nin;
            if (col < CC && nm < NN) out[(size_t)nm * CC + col] = v[t] - lse;
        }
    }
}

extern "C" void kernel_launch(void* const* d_in, const int* in_sizes, int n_in,
                              void* d_out, int out_size, void* d_ws, size_t ws_size,
                              hipStream_t stream) {
    const float* x      = (const float*)d_in[0];
    const int*   ei     = (const int*)d_in[1];
    const float* enc_Wl = (const float*)d_in[2];
    const float* enc_Wr = (const float*)d_in[3];
    const float* enc_b  = (const float*)d_in[4];
    const float* lay_Wl = (const float*)d_in[5];
    const float* lay_Wr = (const float*)d_in[6];
    const float* lay_b  = (const float*)d_in[7];
    const float* dec_Wl = (const float*)d_in[8];
    const float* dec_Wr = (const float*)d_in[9];
    const float* dec_b  = (const float*)d_in[10];
    float* out = (float*)d_out;

    const int* src = ei;
    const int* dst = ei + EE;

    // ---- workspace carve (256B aligned), total ~36 MB ----
    char* p = (char*)d_ws;
    auto carve = [&](size_t bytes) {
        char* r = p;
        p += (bytes + 255) & ~(size_t)255;
        return r;
    };
    int*            counts = (int*)carve(NN * 4);
    unsigned short* csr    = (unsigned short*)carve((size_t)NN * CAP * 2);
    unsigned short* h1     = (unsigned short*)carve((size_t)NN * HH * 2);
    unsigned short* h2     = (unsigned short*)carve((size_t)NN * HH * 2);  // also xb
    unsigned short* tbuf   = (unsigned short*)carve((size_t)NN * 48 * 2 + 256);
    unsigned*       perm   = (unsigned*)carve((size_t)NSLOT * 4);
    int*            aux    = (int*)carve(64 * 4);   // [0..10] hist, [16..26] fill, [32..42] base
    unsigned short* wf[8];
    for (int i = 0; i < 6; ++i) wf[i] = (unsigned short*)carve(HH * HH * 2);
    wf[6] = (unsigned short*)carve(HH * 48 * 2);
    wf[7] = (unsigned short*)carve(HH * 48 * 2);

    // prep: weight swizzles + counts zero + x->bf16 + perm sentinel/aux zero (one launch)
    {
        PrepArgs a;
        a.wsrc[0] = enc_Wl; a.wsrc[1] = enc_Wr;
        a.wsrc[2] = lay_Wl; a.wsrc[3] = lay_Wr;
        a.wsrc[4] = lay_Wl + HH * HH; a.wsrc[5] = lay_Wr + HH * HH;
        a.wsrc[6] = dec_Wl; a.wsrc[7] = dec_Wr;
        for (int i = 0; i < 8; ++i) a.wdst[i] = wf[i];
        a.counts = counts;
        a.x = x;
        a.xb = (unsigned*)h2;
        a.perm = perm;
        a.aux = aux;
        k_prep<<<432 + XCB + PFB, 256, 0, stream>>>(a);
    }

    // padded-CSR build (ushort), then degree-class sort of nodes into perm
    k_build<<<(EE + 255) / 256, 256, 0, stream>>>(src, dst, counts, csr);
    k_hist<<<(NN + 255) / 256, 256, 0, stream>>>(counts, aux);
    k_prefix<<<1, 64, 0, stream>>>(aux, aux + 32);
    k_place<<<(NN + 255) / 256, 256, 0, stream>>>(counts, aux + 32, aux + 16, perm);

    // layers: 3136 blocks x 16 waves (1 slot/wave); layer 3 fuses t = h1 @ dec_Wl
    k_layer<0><<<NBLK, 1024, 0, stream>>>(h2, perm, csr, wf[0], wf[1], enc_b,      h1, nullptr, nullptr);
    k_layer<0><<<NBLK, 1024, 0, stream>>>(h1, perm, csr, wf[2], wf[3], lay_b,      h2, nullptr, nullptr);
    k_layer<1><<<NBLK, 1024, 0, stream>>>(h2, perm, csr, wf[4], wf[5], lay_b + HH, h1, wf[6], tbuf);

    // decoder: gather t + h1@Wr + log_softmax
    k_dec<<<NBLK, 1024, 0, stream>>>(tbuf, h1, perm, csr, wf[7], dec_b, out);
}

// Round 7
// 308.365 us; speedup vs baseline: 1.2053x; 1.2053x over previous
//
#include <hip/hip_runtime.h>
#include <hip/hip_bf16.h>

#define NN 50000
#define EE 600000
#define HH 128
#define CC 40
#define NEG 0.1f
#define CAP 40      // padded-CSR capacity; P(deg>40) ~ 1e-10 for Binom(600k, 1/50k)
#define NSLOT 50176 // 16-padded class-sorted slots
#define NBLK (NSLOT / 16)   // 3136

typedef __attribute__((ext_vector_type(8))) short bf16x8;
typedef __attribute__((ext_vector_type(4))) float f32x4;
typedef __attribute__((ext_vector_type(4))) unsigned uint4v;

__device__ __forceinline__ unsigned short f2bf(float f) {
    unsigned u = __float_as_uint(f);
    unsigned r = u + 0x7fffu + ((u >> 16) & 1u);
    return (unsigned short)(r >> 16);
}
__device__ __forceinline__ float bfhi(unsigned v) { return __uint_as_float(v & 0xFFFF0000u); }
__device__ __forceinline__ float bflo(unsigned v) { return __uint_as_float(v << 16); }

// ---------------- padded-CSR build: one edge per thread; ushort entries ----------------
__global__ void k_build(const int* __restrict__ src, const int* __restrict__ dst,
                        int* __restrict__ counts, unsigned short* __restrict__ csr) {
    int e = blockIdx.x * blockDim.x + threadIdx.x;
    if (e < EE) {
        int d = dst[e];
        if ((unsigned)d < (unsigned)NN) {
            int sl = atomicAdd(&counts[d], 1);
            if (sl < CAP) csr[d * CAP + sl] = (unsigned short)src[e];
        }
    }
}

// ---------------- degree-class sort: hist -> prefix -> place ----------------
__global__ void k_hist(const int* __restrict__ counts, int* __restrict__ hist) {
    __shared__ int lh[16];
    if (threadIdx.x < 16) lh[threadIdx.x] = 0;
    __syncthreads();
    int n = blockIdx.x * 256 + threadIdx.x;
    if (n < NN) {
        int c = counts[n]; c = c < CAP ? c : CAP;
        atomicAdd(&lh[(c + 3) >> 2], 1);
    }
    __syncthreads();
    if (threadIdx.x < 11) atomicAdd(&hist[threadIdx.x], lh[threadIdx.x]);
}

__global__ void k_prefix(const int* __restrict__ hist, int* __restrict__ base) {
    if (threadIdx.x == 0) {
        int acc = 0;
        for (int r = 10; r >= 0; --r) {   // descending: long blocks first
            base[r] = acc;
            acc += (hist[r] + 15) & ~15;
        }
    }
}

// hierarchical-atomic place: LDS class counts -> 1 global atomic per class per block
__global__ void k_place(const int* __restrict__ counts, const int* __restrict__ base,
                        int* __restrict__ fill, unsigned* __restrict__ perm) {
    __shared__ int lcnt[16];
    __shared__ int lbase[16];
    int t = threadIdx.x;
    if (t < 16) lcnt[t] = 0;
    __syncthreads();
    int n = blockIdx.x * 256 + t;
    int r = 0, lslot = 0, c = 0;
    if (n < NN) {
        c = counts[n]; c = c < CAP ? c : CAP;
        r = (c + 3) >> 2;
        lslot = atomicAdd(&lcnt[r], 1);
    }
    __syncthreads();
    if (t < 11 && lcnt[t] > 0) lbase[t] = atomicAdd(&fill[t], lcnt[t]);
    __syncthreads();
    if (n < NN) {
        int slot = base[r] + lbase[r] + lslot;
        if (slot >= 0 && slot < NSLOT) perm[slot] = (unsigned)n | ((unsigned)c << 16);
    }
}

// ---------------- k_prep: weight swizzle + counts zero + x->bf16 + perm/aux init ----------------
struct PrepArgs {
    const float* wsrc[8];
    unsigned short* wdst[8];
    int* counts;
    const float* x;
    unsigned* xb;
    unsigned* perm;
    int* aux;
};

template <int DOUT, int DOUTP>
__device__ __forceinline__ void swz_one(const float* __restrict__ W,
                                        unsigned short* __restrict__ dstf, int idx) {
    int k = idx / DOUTP, n = idx % DOUTP;
    unsigned short val = (n < DOUT) ? f2bf(W[k * DOUT + n]) : (unsigned short)0;
    int kt = k >> 5, kin = k & 31, nt = n >> 4, nin = n & 15;
    int lane = ((kin >> 3) << 4) | nin;
    int j = kin & 7;
    int NT = DOUTP >> 4;
    dstf[(((kt * NT + nt) * 64) + lane) * 8 + j] = val;
}

#define XCB ((NN * HH / 4 + 255) / 256)   // 6250 xcast blocks
#define PFB ((NSLOT + 255) / 256)         // 196 perm-fill blocks

__global__ void k_prep(PrepArgs a) {
    int b = blockIdx.x;
    if (b < 384) {
        int tid = b * 256 + threadIdx.x;
        if (tid < NN) a.counts[tid] = 0;
        int which = b >> 6;
        int idx = (b & 63) * 256 + threadIdx.x;
        swz_one<HH, HH>(a.wsrc[which], a.wdst[which], idx);
    } else if (b < 432) {
        int bb = b - 384;
        int which = 6 + bb / 24;
        int idx = (bb % 24) * 256 + threadIdx.x;
        swz_one<CC, 48>(a.wsrc[which], a.wdst[which], idx);
    } else if (b < 432 + XCB) {
        int t = (b - 432) * 256 + threadIdx.x;
        if (t < NN * HH / 4) {
            float4 v = ((const float4*)a.x)[t];
            uint2 o;
            o.x = ((unsigned)f2bf(v.y) << 16) | f2bf(v.x);
            o.y = ((unsigned)f2bf(v.w) << 16) | f2bf(v.z);
            ((uint2*)a.xb)[t] = o;
        }
    } else {
        int i = (b - (432 + XCB)) * 256 + threadIdx.x;
        if (i < NSLOT) a.perm[i] = 0xFFFFFFFFu;   // sentinel
        if (i < 64) a.aux[i] = 0;                  // hist + fill
    }
}

// ---------------- gather batch: indices from SGPR-resident csr words (scalar path) ----------------
template <int R>
__device__ __forceinline__ void gather_batch(const unsigned long long* cw,
                                             const uint4v* __restrict__ hw4,
                                             int s, int sh16, int gg, int cnt, int base_r,
                                             float (&acc)[8]) {
    uint4v vb[R];
#pragma unroll
    for (int r = 0; r < R; ++r) {
        unsigned long long w = cw[base_r + r];
        unsigned half = (s & 2) ? (unsigned)(w >> 32) : (unsigned)w;
        unsigned idx = (half >> sh16) & 0xffffu;
        idx = idx < (unsigned)NN ? idx : 0u;
        vb[r] = hw4[(size_t)idx * 16 + gg];
    }
#pragma unroll
    for (int r = 0; r < R; ++r) {
        if ((base_r + r) * 4 + s < cnt) {
            acc[0] += bflo(vb[r].x); acc[1] += bfhi(vb[r].x);
            acc[2] += bflo(vb[r].y); acc[3] += bfhi(vb[r].y);
            acc[4] += bflo(vb[r].z); acc[5] += bfhi(vb[r].z);
            acc[6] += bflo(vb[r].w); acc[7] += bfhi(vb[r].w);
        }
    }
}

// ---------------- layer kernel: scalar-path csr, LDS self rows, coalesced out ----------------
// Block = 1024 thr = 16 waves = 16 slots (1 node/wave). lane = s*16+gg: s = edge slot 0..3,
// gg = uint4 dim-group (full 256B row per round). Wave-uniform scalar switch on rounds.
template <int MODE>
__global__ __launch_bounds__(1024, 8) void k_layer(
    const unsigned short* __restrict__ hin,    // [N][128] bf16 (node space)
    const unsigned* __restrict__ perm,         // [NSLOT] node|cnt<<16
    const unsigned short* __restrict__ csr,    // [N][CAP] ushort src ids
    const unsigned short* __restrict__ B1f, const unsigned short* __restrict__ B2f,
    const float* __restrict__ bias, unsigned short* __restrict__ out,
    const unsigned short* __restrict__ Tf, unsigned short* __restrict__ tOut) {
    __shared__ unsigned lds[16][72];       // agg tile; later reused as lsh [16][144] shorts
    __shared__ unsigned selfLds[16][68];   // self rows, 272B stride (2-way-free banks)
    __shared__ int nodeTab[16];
    int wid = threadIdx.x >> 6;
    int lane = threadIdx.x & 63;
    int m0 = blockIdx.x * 16;
    int gg = lane & 15;
    int s = lane >> 4;
    int sh16 = (s & 1) * 16;
    const uint4v* hw4 = (const uint4v*)hin;

    // wave-uniform perm entry via scalar path
    int slot = __builtin_amdgcn_readfirstlane(m0 + wid);
    unsigned pe = perm[slot];
    int node = (int)(pe & 0xffffu);
    int cnt = (int)((pe >> 16) & 0xffffu);
    int valid = node < NN;
    if (lane == 0) nodeTab[wid] = valid ? node : (1 << 30);
    int rounds = valid ? (cnt + 3) >> 2 : 0;
    rounds = rounds < 10 ? rounds : 10;
    float sc = 1.0f / (float)((valid && cnt > 0) ? cnt : 1);

    // coalesced self-row stage: 1 instr/wave (256B), replaces scattered a2 loads
    if (lane < 16) {
        uint4v sv = hw4[(size_t)(valid ? node : 0) * 16 + lane];
        *(uint4v*)&selfLds[wid][lane * 4] = sv;
    }

    // whole csr list (80B) via scalar loads, uniform base
    const unsigned long long* cr8 =
        (const unsigned long long*)(csr + (size_t)(valid ? node : 0) * CAP);
    unsigned long long cw[10];
#pragma unroll
    for (int r = 0; r < 10; ++r) cw[r] = cr8[r];

    float acc[8];
#pragma unroll
    for (int d = 0; d < 8; ++d) acc[d] = 0.f;

    switch (rounds) {   // scalar switch (class-sorted -> block-uniform)
        case 0: break;
        case 1: gather_batch<1>(cw, hw4, s, sh16, gg, cnt, 0, acc); break;
        case 2: gather_batch<2>(cw, hw4, s, sh16, gg, cnt, 0, acc); break;
        case 3: gather_batch<3>(cw, hw4, s, sh16, gg, cnt, 0, acc); break;
        case 4: gather_batch<4>(cw, hw4, s, sh16, gg, cnt, 0, acc); break;
        case 5: gather_batch<5>(cw, hw4, s, sh16, gg, cnt, 0, acc); break;
        case 6: gather_batch<3>(cw, hw4, s, sh16, gg, cnt, 0, acc);
                gather_batch<3>(cw, hw4, s, sh16, gg, cnt, 3, acc); break;
        case 7: gather_batch<4>(cw, hw4, s, sh16, gg, cnt, 0, acc);
                gather_batch<3>(cw, hw4, s, sh16, gg, cnt, 4, acc); break;
        case 8: gather_batch<4>(cw, hw4, s, sh16, gg, cnt, 0, acc);
                gather_batch<4>(cw, hw4, s, sh16, gg, cnt, 4, acc); break;
        case 9: gather_batch<5>(cw, hw4, s, sh16, gg, cnt, 0, acc);
                gather_batch<4>(cw, hw4, s, sh16, gg, cnt, 5, acc); break;
        default: gather_batch<5>(cw, hw4, s, sh16, gg, cnt, 0, acc);
                 gather_batch<5>(cw, hw4, s, sh16, gg, cnt, 5, acc); break;
    }

    // reduce over slot bits (lane bits 4,5)
#pragma unroll
    for (int d = 0; d < 8; ++d) {
        float t = acc[d];
        t += __shfl_xor(t, 16, 64);
        t += __shfl_xor(t, 32, 64);
        acc[d] = t * sc;
    }
    if (lane < 16) {   // s == 0, gg == lane
        unsigned w4[4];
        w4[0] = ((unsigned)f2bf(acc[1]) << 16) | f2bf(acc[0]);
        w4[1] = ((unsigned)f2bf(acc[3]) << 16) | f2bf(acc[2]);
        w4[2] = ((unsigned)f2bf(acc[5]) << 16) | f2bf(acc[4]);
        w4[3] = ((unsigned)f2bf(acc[7]) << 16) | f2bf(acc[6]);
        *(uint4v*)&lds[wid][gg * 4] = *(uint4v*)w4;
    }
    __syncthreads();

    // ---- MFMA: A1 from LDS agg tile, A2 from LDS self rows; waves 0..7, 1 col-tile per wave ----
    int nin = lane & 15;
    int kq = lane >> 4;
    unsigned short hv[4];

    if (wid < 8) {
        const unsigned* arow = &lds[nin][0];
        const unsigned short* srow = (const unsigned short*)&selfLds[nin][0];
        f32x4 acc1 = (f32x4){0.f, 0.f, 0.f, 0.f};

#pragma unroll
        for (int kt = 0; kt < 4; ++kt) {
            bf16x8 a1 = *(const bf16x8*)(arow + kt * 16 + kq * 4);
            bf16x8 a2 = *(const bf16x8*)(srow + kt * 32 + kq * 8);
            bf16x8 b1 = *(const bf16x8*)(B1f + (((kt * 8 + wid) * 64) + lane) * 8);
            acc1 = __builtin_amdgcn_mfma_f32_16x16x32_bf16(a1, b1, acc1, 0, 0, 0);
            bf16x8 b2 = *(const bf16x8*)(B2f + (((kt * 8 + wid) * 64) + lane) * 8);
            acc1 = __builtin_amdgcn_mfma_f32_16x16x32_bf16(a2, b2, acc1, 0, 0, 0);
        }

        // C/D: col = lane&15, row = (lane>>4)*4 + reg
        int col = wid * 16 + nin;
        float bv = bias[col];
#pragma unroll
        for (int r = 0; r < 4; ++r) {
            float v = acc1[r] + bv;
            v = fmaxf(v, NEG * v);
            hv[r] = f2bf(v);
        }
    }

    // ---- stage lrelu'd tile to LDS, coalesced 256B row stores (1 instr/wave) ----
    __syncthreads();   // all a1/a2 LDS reads done
    unsigned short* lsh = (unsigned short*)&lds[0][0];   // [16][144] shorts
    if (wid < 8) {
        int col = wid * 16 + nin;
#pragma unroll
        for (int r = 0; r < 4; ++r) lsh[(kq * 4 + r) * 144 + col] = hv[r];
    }
    __syncthreads();
    {
        int nm = nodeTab[wid];   // wave-uniform
        if (nm < NN && lane < 16)
            *(uint4v*)&out[(size_t)nm * HH + lane * 8] = *(uint4v*)&lsh[wid * 144 + lane * 8];
    }

    if (MODE == 1) {
        // waves 0..2 compute t = tile @ dec_Wl (16x48) from lsh
        if (wid < 3) {
            f32x4 at = (f32x4){0.f, 0.f, 0.f, 0.f};
#pragma unroll
            for (int kt = 0; kt < 4; ++kt) {
                bf16x8 a = *(const bf16x8*)&lsh[nin * 144 + kt * 32 + kq * 8];
                bf16x8 b = *(const bf16x8*)(Tf + (((kt * 3 + wid) * 64) + lane) * 8);
                at = __builtin_amdgcn_mfma_f32_16x16x32_bf16(a, b, at, 0, 0, 0);
            }
#pragma unroll
            for (int r = 0; r < 4; ++r) {
                int nm = nodeTab[kq * 4 + r];
                if (nm < NN) tOut[(size_t)nm * 48 + wid * 16 + nin] = f2bf(at[r]);
            }
        }
    }
}

// ---------------- k_dec gather batch: 8 slots x 6(+2 dup) uint4 groups, 96B rows ----------------
// entry index e = r*8+s -> ull word 2r+(s>>2), 32b half (s>>1)&1, 16b pos s&1.
template <int R>
__device__ __forceinline__ void gatherd_batch(const unsigned long long* cw,
                                              const uint4v* __restrict__ t4,
                                              int s, int sh16, int g6, int cnt,
                                              float (&acc)[8]) {
    uint4v vb[R];
#pragma unroll
    for (int r = 0; r < R; ++r) {
        unsigned long long w = (s & 4) ? cw[2 * r + 1] : cw[2 * r];
        unsigned half = (s & 2) ? (unsigned)(w >> 32) : (unsigned)w;
        unsigned idx = (half >> sh16) & 0xffffu;
        idx = idx < (unsigned)NN ? idx : 0u;
        vb[r] = t4[(size_t)idx * 6 + g6];
    }
#pragma unroll
    for (int r = 0; r < R; ++r) {
        if (r * 8 + s < cnt) {
            acc[0] += bflo(vb[r].x); acc[1] += bfhi(vb[r].x);
            acc[2] += bflo(vb[r].y); acc[3] += bfhi(vb[r].y);
            acc[4] += bflo(vb[r].z); acc[5] += bfhi(vb[r].z);
            acc[6] += bflo(vb[r].w); acc[7] += bfhi(vb[r].w);
        }
    }
}

// ---------------- k_dec: gather t + h1@Wr + bias + log_softmax ----------------
__global__ __launch_bounds__(1024, 8) void k_dec(
    const unsigned short* __restrict__ tbuf,   // [N][48] bf16, 96B rows
    const unsigned short* __restrict__ h1,
    const unsigned* __restrict__ perm,
    const unsigned short* __restrict__ csr,
    const unsigned short* __restrict__ B2f, const float* __restrict__ bias,
    float* __restrict__ out) {
    __shared__ float aggT[16][52];
    __shared__ int nodeTab[16];
    int wid = threadIdx.x >> 6;
    int lane = threadIdx.x & 63;
    int m0 = blockIdx.x * 16;
    int g = lane & 7;
    int g6 = g < 6 ? g : g - 6;        // lanes 6,7 duplicate slices 0,1 (same cache lines)
    int s = lane >> 3;                 // 8 edge-slots
    int sh16 = (s & 1) * 16;
    const uint4v* t4 = (const uint4v*)tbuf;

    int slot = __builtin_amdgcn_readfirstlane(m0 + wid);
    unsigned pe = perm[slot];
    int node = (int)(pe & 0xffffu);
    int cnt = (int)((pe >> 16) & 0xffffu);
    int valid = node < NN;
    if (lane == 0) nodeTab[wid] = valid ? node : (1 << 30);
    int rounds = valid ? (cnt + 7) >> 3 : 0;   // <= 5
    rounds = rounds < 5 ? rounds : 5;
    float sc = 1.0f / (float)((valid && cnt > 0) ? cnt : 1);

    const unsigned long long* cr8 =
        (const unsigned long long*)(csr + (size_t)(valid ? node : 0) * CAP);
    unsigned long long cw[10];
#pragma unroll
    for (int r = 0; r < 10; ++r) cw[r] = cr8[r];

    float acc[8];
#pragma unroll
    for (int d = 0; d < 8; ++d) acc[d] = 0.f;

    switch (rounds) {
        case 0: break;
        case 1: gatherd_batch<1>(cw, t4, s, sh16, g6, cnt, acc); break;
        case 2: gatherd_batch<2>(cw, t4, s, sh16, g6, cnt, acc); break;
        case 3: gatherd_batch<3>(cw, t4, s, sh16, g6, cnt, acc); break;
        case 4: gatherd_batch<4>(cw, t4, s, sh16, g6, cnt, acc); break;
        default: gatherd_batch<5>(cw, t4, s, sh16, g6, cnt, acc); break;
    }

    // reduce over slot bits (lane bits 3..5)
#pragma unroll
    for (int d = 0; d < 8; ++d) {
        float t = acc[d];
        t += __shfl_xor(t, 8, 64);
        t += __shfl_xor(t, 16, 64);
        t += __shfl_xor(t, 32, 64);
        acc[d] = t * sc;
    }
    if (s == 0 && g < 6) {
        float4 p0, p1;
        p0.x = acc[0]; p0.y = acc[1]; p0.z = acc[2]; p0.w = acc[3];
        p1.x = acc[4]; p1.y = acc[5]; p1.z = acc[6]; p1.w = acc[7];
        *(float4*)&aggT[wid][8 * g] = p0;
        *(float4*)&aggT[wid][8 * g + 4] = p1;
    }
    __syncthreads();
    if (wid != 0) return;

    int nin = lane & 15, kq = lane >> 4;
    int node2 = nodeTab[nin];
    int na = node2 < NN ? node2 : 0;
    f32x4 acc2[3];
#pragma unroll
    for (int j = 0; j < 3; ++j) acc2[j] = (f32x4){0.f, 0.f, 0.f, 0.f};
#pragma unroll
    for (int kt = 0; kt < 4; ++kt) {
        bf16x8 a2 = *(const bf16x8*)(h1 + (size_t)na * HH + kt * 32 + kq * 8);
#pragma unroll
        for (int j = 0; j < 3; ++j) {
            bf16x8 b2 = *(const bf16x8*)(B2f + (((kt * 3 + j) * 64) + lane) * 8);
            acc2[j] = __builtin_amdgcn_mfma_f32_16x16x32_bf16(a2, b2, acc2[j], 0, 0, 0);
        }
    }
    float bv[3];
#pragma unroll
    for (int t = 0; t < 3; ++t) {
        int col = t * 16 + nin;
        bv[t] = (col < CC) ? bias[col] : 0.f;
    }
#pragma unroll
    for (int r = 0; r < 4; ++r) {
        int ml = kq * 4 + r;
        int nm = nodeTab[ml];
        float v[3];
        float mx = -1e30f;
#pragma unroll
        for (int t = 0; t < 3; ++t) {
            int col = t * 16 + nin;
            v[t] = acc2[t][r] + aggT[ml][col] + bv[t];
            if (col < CC) mx = fmaxf(mx, v[t]);
        }
        for (int off = 1; off < 16; off <<= 1) mx = fmaxf(mx, __shfl_xor(mx, off, 64));
        float sm = 0.f;
#pragma unroll
        for (int t = 0; t < 3; ++t) {
            int col = t * 16 + nin;
            if (col < CC) sm += expf(v[t] - mx);
        }
        for (int off = 1; off < 16; off <<= 1) sm += __shfl_xor(sm, off, 64);
        float lse = mx + logf(sm);
#pragma unroll
        for (int t = 0; t < 3; ++t) {
            int col = t * 16 + nin;
            if (col < CC && nm < NN) out[(size_t)nm * CC + col] = v[t] - lse;
        }
    }
}

extern "C" void kernel_launch(void* const* d_in, const int* in_sizes, int n_in,
                              void* d_out, int out_size, void* d_ws, size_t ws_size,
                              hipStream_t stream) {
    const float* x      = (const float*)d_in[0];
    const int*   ei     = (const int*)d_in[1];
    const float* enc_Wl = (const float*)d_in[2];
    const float* enc_Wr = (const float*)d_in[3];
    const float* enc_b  = (const float*)d_in[4];
    const float* lay_Wl = (const float*)d_in[5];
    const float* lay_Wr = (const float*)d_in[6];
    const float* lay_b  = (const float*)d_in[7];
    const float* dec_Wl = (const float*)d_in[8];
    const float* dec_Wr = (const float*)d_in[9];
    const float* dec_b  = (const float*)d_in[10];
    float* out = (float*)d_out;

    const int* src = ei;
    const int* dst = ei + EE;

    // ---- workspace carve (256B aligned), total ~36 MB ----
    char* p = (char*)d_ws;
    auto carve = [&](size_t bytes) {
        char* r = p;
        p += (bytes + 255) & ~(size_t)255;
        return r;
    };
    int*            counts = (int*)carve(NN * 4);
    unsigned short* csr    = (unsigned short*)carve((size_t)NN * CAP * 2);
    unsigned short* h1     = (unsigned short*)carve((size_t)NN * HH * 2);
    unsigned short* h2     = (unsigned short*)carve((size_t)NN * HH * 2);  // also xb
    unsigned short* tbuf   = (unsigned short*)carve((size_t)NN * 48 * 2 + 256);
    unsigned*       perm   = (unsigned*)carve((size_t)NSLOT * 4);
    int*            aux    = (int*)carve(64 * 4);   // [0..10] hist, [16..26] fill, [32..42] base
    unsigned short* wf[8];
    for (int i = 0; i < 6; ++i) wf[i] = (unsigned short*)carve(HH * HH * 2);
    wf[6] = (unsigned short*)carve(HH * 48 * 2);
    wf[7] = (unsigned short*)carve(HH * 48 * 2);

    // prep: weight swizzles + counts zero + x->bf16 + perm sentinel/aux zero (one launch)
    {
        PrepArgs a;
        a.wsrc[0] = enc_Wl; a.wsrc[1] = enc_Wr;
        a.wsrc[2] = lay_Wl; a.wsrc[3] = lay_Wr;
        a.wsrc[4] = lay_Wl + HH * HH; a.wsrc[5] = lay_Wr + HH * HH;
        a.wsrc[6] = dec_Wl; a.wsrc[7] = dec_Wr;
        for (int i = 0; i < 8; ++i) a.wdst[i] = wf[i];
        a.counts = counts;
        a.x = x;
        a.xb = (unsigned*)h2;
        a.perm = perm;
        a.aux = aux;
        k_prep<<<432 + XCB + PFB, 256, 0, stream>>>(a);
    }

    // padded-CSR build (ushort), then degree-class sort of nodes into perm
    k_build<<<(EE + 255) / 256, 256, 0, stream>>>(src, dst, counts, csr);
    k_hist<<<(NN + 255) / 256, 256, 0, stream>>>(counts, aux);
    k_prefix<<<1, 64, 0, stream>>>(aux, aux + 32);
    k_place<<<(NN + 255) / 256, 256, 0, stream>>>(counts, aux + 32, aux + 16, perm);

    // layers: 3136 blocks x 16 waves (1 slot/wave); layer 3 fuses t = h1 @ dec_Wl
    k_layer<0><<<NBLK, 1024, 0, stream>>>(h2, perm, csr, wf[0], wf[1], enc_b,      h1, nullptr, nullptr);
    k_layer<0><<<NBLK, 1024, 0, stream>>>(h1, perm, csr, wf[2], wf[3], lay_b,      h2, nullptr, nullptr);
    k_layer<1><<<NBLK, 1024, 0, stream>>>(h2, perm, csr, wf[4], wf[5], lay_b + HH, h1, wf[6], tbuf);

    // decoder: gather t + h1@Wr + log_softmax
    k_dec<<<NBLK, 1024, 0, stream>>>(tbuf, h1, perm, csr, wf[7], dec_b, out);
}